// Round 6
// baseline (31.825 us; speedup 1.0000x reference)
//
#include <hip/hip_runtime.h>
#include <math.h>

#define NCLS 20
#define B_N 128
#define A_N 5
#define H_N 26
#define W_N 26
#define HW_N (H_N * W_N)            // 676
#define M_N 64
#define CH_N (5 + NCLS)             // 25
#define HALF_LOC (HW_N / 2)         // 338 locations per half-plane
#define BLK_T 384                   // 6 waves, 1 loc/thread (338 active)
#define WAVES_PB 6
#define WIN_BLKS B_N                // 128 winner blocks (first in grid)
#define NOOBJ_BLKS (B_N * A_N * 2)  // 1280 half-plane blocks
#define SLOTS_PER_B (A_N * 2)       // 10 per-block slots per batch
#define SENT 1.0e18f

__device__ __forceinline__ float fastrcp(float x) { return __builtin_amdgcn_rcpf(x); }
__device__ __forceinline__ float sigmoidf_(float x) { return fastrcp(1.0f + __expf(-x)); }
__device__ __forceinline__ float rdlane(float v, int m) {
    return __int_as_float(__builtin_amdgcn_readlane(__float_as_int(v), m));
}

// ---------------------------------------------------------------------------
// Main kernel: 128 winner blocks (1 active wave each) + 1280 noobj blocks.
// gt boxes live in per-lane REGISTERS (lane m holds gt m); inner loop
// broadcasts via v_readlane -> pure-VALU loop, zero LDS traffic.
// ---------------------------------------------------------------------------
__global__ __launch_bounds__(BLK_T, 8) void main_kernel(
    const float* __restrict__ outputs, const float* __restrict__ targets,
    const float* __restrict__ anchors,
    float* __restrict__ A_part, float* __restrict__ H_part,
    int* __restrict__ any_part,
    float* __restrict__ Gb, float* __restrict__ Asub, float* __restrict__ Hsub,
    int* __restrict__ nobjArr) {
    int blk = blockIdx.x;
    bool winnerBlk = (blk < WIN_BLKS);
    int tid = threadIdx.x;
    if (winnerBlk && tid >= M_N) return;     // winner blocks: wave 0 only
    int lane = tid & 63;

    int b, a, half;
    if (winnerBlk) { b = blk; a = 0; half = 0; }
    else {
        int nb = blk - WIN_BLKS;
        int plane = nb >> 1; half = nb & 1;
        b = plane / A_N; a = plane % A_N;
    }

    __shared__ int skey[M_N];                // winner-resolution (256 B)
    __shared__ float rA[WAVES_PB], rH[WAVES_PB];
    __shared__ int rAny[WAVES_PB];

    // ---- per-lane gt staging: lane holds gt[lane] in registers ----
    const float* trow = targets + ((size_t)b * M_N + lane) * 5;
    float tc = trow[0], tx = trow[1], ty = trow[2], tw = trow[3], th = trow[4];

    // ---- early-issue O loads (noobj path), overlap with gt build ----
    float O0 = 0, O1 = 0, O2 = 0, O3 = 0, O4 = 0;
    int hw = 0; bool act = false;
    if (!winnerBlk) {
        act = (tid < HALF_LOC);
        hw = half * HALF_LOC + (act ? tid : 0);
        const float* op = outputs +
            ((size_t)b * (A_N * CH_N) + (size_t)a * CH_N) * HW_N + hw;
        O0 = op[0 * HW_N]; O1 = op[1 * HW_N]; O2 = op[2 * HW_N];
        O3 = op[3 * HW_N]; O4 = op[4 * HW_N];
    }

    bool valid = (tc + tx + ty + tw + th) > 0.0f;   // valid rows are a prefix
    unsigned long long mask = __ballot(valid);
    int nobj = __popcll(mask);
    float gx = tx * (float)W_N, gy = ty * (float)H_N;
    float gw = tw * (float)W_N, gh = th * (float)H_N;
    float g0, g1, g2, g3, ga;                       // tlx, tly, brx, bry, area
    if (valid) {
        g0 = gx - gw * 0.5f; g1 = gy - gh * 0.5f;
        g2 = gx + gw * 0.5f; g3 = gy + gh * 0.5f; ga = gw * gh;
    } else {                                        // sentinel: inter=0, ga=0
        g0 = SENT; g1 = SENT; g2 = SENT; g3 = SENT; ga = 0.0f;
    }

    if (winnerBlk) {
        // ================= winner path (wave 0, lane == m) =================
        float G = 0.0f, c2A = 0.0f, c2H = 0.0f;
        int m = lane;
        int cell = (int)floorf(gy) * W_N + (int)floorf(gx);
        cell = min(max(cell, 0), HW_N - 1);
        int ccx = cell % W_N, ccy = cell / W_N;
        float best = -1.0f;
        int ai = 0; float aw = 1.0f, ah = 1.0f;
        #pragma unroll
        for (int aa = 0; aa < A_N; ++aa) {
            float anw = anchors[2 * aa], anh = anchors[2 * aa + 1];
            float atlx = (float)ccx + 0.5f - anw * 0.5f;
            float atly = (float)ccy + 0.5f - anh * 0.5f;
            float ix = fminf(atlx + anw, g2) - fmaxf(atlx, g0);
            float iy = fminf(atly + anh, g3) - fmaxf(atly, g1);
            float inter = fmaxf(ix, 0.0f) * fmaxf(iy, 0.0f);
            float ov = inter * fastrcp(anw * anh + ga - inter);
            if (ov > best) { best = ov; ai = aa; aw = anw; ah = anh; }
        }
        int mykey = cell * A_N + ai;
        skey[m] = valid ? mykey : (-1 - m);         // distinct non-matching keys
        __builtin_amdgcn_s_waitcnt(0);              // order LDS write->read in-wave

        // winner = last valid m holding its key (lax.scan overwrite semantics)
        bool winner = valid;
        if (valid) {
            for (int mm = m + 1; mm < M_N; ++mm)
                if (skey[mm] == mykey) winner = false;
        }

        if (winner) {
            size_t obase = ((size_t)b * (A_N * CH_N) + (size_t)ai * CH_N) * HW_N + cell;
            float o0 = outputs[obase + 0 * HW_N];
            float o1 = outputs[obase + 1 * HW_N];
            float o2 = outputs[obase + 2 * HW_N];
            float o3 = outputs[obase + 3 * HW_N];
            float o4 = outputs[obase + 4 * HW_N];
            float sx = sigmoidf_(o0), sy = sigmoidf_(o1);
            float ew = __expf(o2), eh = __expf(o3);
            float conf = sigmoidf_(o4);
            float px = sx + (float)ccx, py = sy + (float)ccy;
            float pw = ew * aw, ph = eh * ah;
            float tlx = px - pw * 0.5f, tly = py - ph * 0.5f;
            float brx = px + pw * 0.5f, bry = py + ph * 0.5f;
            float pa = pw * ph;

            float mi = 0.0f, maxdW = -1e30f;
            for (int mm = 0; mm < nobj; ++mm) {     // readlane ignores exec mask
                float q0 = rdlane(g0, mm), q1 = rdlane(g1, mm);
                float q2 = rdlane(g2, mm), q3 = rdlane(g3, mm);
                float qa = rdlane(ga, mm);
                float ix = fminf(brx, q2) - fmaxf(tlx, q0);
                float iy = fminf(bry, q3) - fmaxf(tly, q1);
                float in = fmaxf(ix, 0.0f) * fmaxf(iy, 0.0f);
                mi = fmaxf(mi, in * fastrcp(pa + qa - in));
                maxdW = fmaxf(maxdW, fmaf(3.0f, in, -(pa + qa)));
            }

            float dcf = conf - mi;
            G = dcf * dcf;
            float bs = 2.0f - (pw / (float)W_N) * (ph / (float)H_N);
            float e0 = sx - (gx - (float)ccx);
            float e1 = sy - (gy - (float)ccy);
            float e2 = ew - gw / aw;
            float e3 = eh - gh / ah;
            G += bs * (e0 * e0 + e1 * e1 + e2 * e2 + e3 * e3);

            // class CE, 2-pass (no logits array -> low VGPR)
            int cls = (int)tc;
            float mx = -1e30f;
            #pragma unroll
            for (int c = 0; c < NCLS; ++c)
                mx = fmaxf(mx, outputs[obase + (size_t)(5 + c) * HW_N]);
            float se = 0.0f, tv = 0.0f;
            #pragma unroll
            for (int c = 0; c < NCLS; ++c) {
                float v = outputs[obase + (size_t)(5 + c) * HW_N];
                se += __expf(v - mx);
                if (c == cls) tv = v;
            }
            G += (mx + __logf(se)) - tv;

            c2A = conf * conf;                       // noobj-sum corrections
            c2H = (maxdW >= 0.0f) ? c2A : 0.0f;
        }
        #pragma unroll
        for (int off = 32; off > 0; off >>= 1) {
            G   += __shfl_down(G, off);
            c2A += __shfl_down(c2A, off);
            c2H += __shfl_down(c2H, off);
        }
        if (lane == 0) {
            Gb[b] = G; Asub[b] = c2A; Hsub[b] = c2H; nobjArr[b] = nobj;
        }
    } else {
        // ========== noobj path: 1 location/thread, pure-VALU loop ==========
        unsigned wy = (unsigned)hw / (unsigned)W_N;
        unsigned wx = (unsigned)hw - wy * (unsigned)W_N;
        float aw = anchors[2 * a], ah = anchors[2 * a + 1];
        float sx = sigmoidf_(O0), sy = sigmoidf_(O1);
        float pw = __expf(O2) * aw, ph = __expf(O3) * ah;
        float px = sx + (float)wx, py = sy + (float)wy;
        float tlx = px - pw * 0.5f, tly = py - ph * 0.5f;
        float brx = px + pw * 0.5f, bry = py + ph * 0.5f;
        float pa = pw * ph;

        // sign(maxd): iou >= 0.5 <=> 3*inter - (pa+ga) >= 0 ; > for has_pos
        float maxd = -1e30f;
        int nobj4 = (nobj + 3) & ~3;                 // sentinels are no-ops
        for (int m = 0; m < nobj4; m += 4) {
            #pragma unroll
            for (int k = 0; k < 4; ++k) {
                int mm = m + k;
                float q0 = rdlane(g0, mm), q1 = rdlane(g1, mm);
                float q2 = rdlane(g2, mm), q3 = rdlane(g3, mm);
                float qa = rdlane(ga, mm);
                float ix = fminf(brx, q2) - fmaxf(tlx, q0);
                float iy = fminf(bry, q3) - fmaxf(tly, q1);
                float in = fmaxf(ix, 0.0f) * fmaxf(iy, 0.0f);
                maxd = fmaxf(maxd, fmaf(3.0f, in, -(pa + qa)));
            }
        }
        float locA = 0.0f, locH = 0.0f; bool any = false;
        if (act) {
            float conf = sigmoidf_(O4);
            float c2 = conf * conf;
            locA = c2;
            locH = (maxd >= 0.0f) ? c2 : 0.0f;
            any = (maxd > 0.0f);
        }

        int wany = __any(any) ? 1 : 0;
        #pragma unroll
        for (int off = 32; off > 0; off >>= 1) {
            locA += __shfl_down(locA, off);
            locH += __shfl_down(locH, off);
        }
        int w = tid >> 6;
        if (lane == 0) { rA[w] = locA; rH[w] = locH; rAny[w] = wany; }
        __syncthreads();
        if (tid == 0) {
            float A = 0.0f, Hs = 0.0f; int anyT = 0;
            #pragma unroll
            for (int j = 0; j < WAVES_PB; ++j) {
                A += rA[j]; Hs += rH[j]; anyT |= rAny[j];
            }
            int nb = blk - WIN_BLKS;                 // 10 contiguous slots per b
            A_part[nb] = A; H_part[nb] = Hs; any_part[nb] = anyT;
        }
    }
}

// ---------------------------------------------------------------------------
// Finish: 128 threads, one per batch; fixed-order deterministic reduction.
// ---------------------------------------------------------------------------
__global__ __launch_bounds__(128) void finish_kernel(
    const float* __restrict__ A_part, const float* __restrict__ H_part,
    const int* __restrict__ any_part,
    const float* __restrict__ Gb, const float* __restrict__ Asub,
    const float* __restrict__ Hsub, const int* __restrict__ nobjArr,
    float* __restrict__ out) {
    int t = threadIdx.x;  // == b
    float A = -Asub[t], Hs = -Hsub[t];
    int any = 0;
    #pragma unroll
    for (int j = 0; j < SLOTS_PER_B; ++j) {
        A += A_part[t * SLOTS_PER_B + j];
        Hs += H_part[t * SLOTS_PER_B + j];
        any |= any_part[t * SLOTS_PER_B + j];
    }
    float noobj = (nobjArr[t] > 0) ? (A - (any ? Hs : 0.0f)) : 0.0f;
    float v = Gb[t] + noobj;
    #pragma unroll
    for (int off = 32; off > 0; off >>= 1) v += __shfl_down(v, off);
    __shared__ float r[2];
    if ((t & 63) == 0) r[t >> 6] = v;
    __syncthreads();
    if (t == 0) out[0] = (r[0] + r[1]) / (float)B_N;
}

extern "C" void kernel_launch(void* const* d_in, const int* in_sizes, int n_in,
                              void* d_out, int out_size, void* d_ws, size_t ws_size,
                              hipStream_t stream) {
    const float* outputs = (const float*)d_in[0];
    const float* targets = (const float*)d_in[1];
    const float* anchors = (const float*)d_in[2];
    float* out = (float*)d_out;

    char* ws = (char*)d_ws;
    size_t off = 0;
    float* A_part = (float*)(ws + off); off += 4 * (size_t)NOOBJ_BLKS;
    float* H_part = (float*)(ws + off); off += 4 * (size_t)NOOBJ_BLKS;
    int* any_part = (int*)(ws + off);   off += 4 * (size_t)NOOBJ_BLKS;
    float* Gb = (float*)(ws + off);     off += 4 * B_N;
    float* Asub = (float*)(ws + off);   off += 4 * B_N;
    float* Hsub = (float*)(ws + off);   off += 4 * B_N;
    int* nobjArr = (int*)(ws + off);    off += 4 * B_N;
    // every slot above is unconditionally written each call -> no memset needed

    main_kernel<<<WIN_BLKS + NOOBJ_BLKS, BLK_T, 0, stream>>>(
        outputs, targets, anchors,
        A_part, H_part, any_part, Gb, Asub, Hsub, nobjArr);

    finish_kernel<<<1, 128, 0, stream>>>(A_part, H_part, any_part,
                                         Gb, Asub, Hsub, nobjArr, out);
}

// Round 7
// 22.641 us; speedup vs baseline: 1.4056x; 1.4056x over previous
//
#include <hip/hip_runtime.h>
#include <math.h>

#define NCLS 20
#define B_N 128
#define A_N 5
#define H_N 26
#define W_N 26
#define HW_N (H_N * W_N)            // 676
#define M_N 64
#define CH_N (5 + NCLS)             // 25
#define HALF_LOC (HW_N / 2)         // 338 locations per half-plane
#define HALF_T (HALF_LOC / 2)       // 169 active threads (2 locs each)
#define BLK_T 192                   // 3 waves
#define WIN_BLKS B_N                // 128 winner blocks (first in grid)
#define NOOBJ_BLKS (B_N * A_N * 2)  // 1280 half-plane blocks
#define SLOTS_PER_B (A_N * 2)       // 10 per-block slots per batch
#define SENT 1.0e18f

__device__ __forceinline__ float fastrcp(float x) { return __builtin_amdgcn_rcpf(x); }
__device__ __forceinline__ float sigmoidf_(float x) { return fastrcp(1.0f + __expf(-x)); }

// ---------------------------------------------------------------------------
// Main kernel: 128 winner blocks + 1280 noobj half-plane blocks.
// noobj inner loop: exact wave-uniform y-prune (skipped gts provably cannot
// set the >=0.5 / >0.5 flags), 2 locations/thread, one ds_read_b128 per gt.
// ---------------------------------------------------------------------------
__global__ __launch_bounds__(BLK_T) void main_kernel(
    const float* __restrict__ outputs, const float* __restrict__ targets,
    const float* __restrict__ anchors,
    float* __restrict__ A_part, float* __restrict__ H_part,
    int* __restrict__ any_part,
    float* __restrict__ Gb, float* __restrict__ Asub, float* __restrict__ Hsub,
    int* __restrict__ nobjArr) {
    int blk = blockIdx.x;
    bool winnerBlk = (blk < WIN_BLKS);
    int tid = threadIdx.x;
    int lane = tid & 63;

    int b, a, half;
    if (winnerBlk) { b = blk; a = 0; half = 0; }
    else {
        int nb = blk - WIN_BLKS;
        int plane = nb >> 1; half = nb & 1;
        b = plane / A_N; a = plane % A_N;
    }

    __shared__ float4 sg4[M_N];
    __shared__ int snobj;
    __shared__ float rA[3], rH[3];
    __shared__ int rAny[3];

    // ---- early-issue O-plane loads (noobj), overlap with gt staging ----
    bool act = false;
    float2 O0, O1, O2, O3, O4;
    int hw0 = 0;
    if (!winnerBlk) {
        act = (tid < HALF_T);
        if (act) {
            hw0 = half * HALF_LOC + tid * 2;
            const float* op = outputs +
                ((size_t)b * (A_N * CH_N) + (size_t)a * CH_N) * HW_N + hw0;
            O0 = *(const float2*)(op + 0 * HW_N);
            O1 = *(const float2*)(op + 1 * HW_N);
            O2 = *(const float2*)(op + 2 * HW_N);
            O3 = *(const float2*)(op + 3 * HW_N);
            O4 = *(const float2*)(op + 4 * HW_N);
        }
    }

    // ---- staging: first wave builds gt boxes in LDS ----
    float tc = 0, gx = 0, gy = 0, gw = 0, gh = 0;
    bool valid = false;
    if (tid < M_N) {
        const float* trow = targets + ((size_t)b * M_N + tid) * 5;
        tc = trow[0];
        float tx = trow[1], ty = trow[2], tw = trow[3], th = trow[4];
        valid = (tc + tx + ty + tw + th) > 0.0f;    // valid rows are a prefix
        unsigned long long mask = __ballot(valid);
        if (tid == 0) snobj = __popcll(mask);
        gx = tx * (float)W_N; gy = ty * (float)H_N;
        gw = tw * (float)W_N; gh = th * (float)H_N;
        sg4[tid] = make_float4(gx - gw * 0.5f, gy - gh * 0.5f,
                               gx + gw * 0.5f, gy + gh * 0.5f);
    }
    __syncthreads();
    int nobj = snobj;

    if (winnerBlk) {
        if (tid >= M_N) return;                     // waves 1,2 done
        // ================= winner path (wave 0, lane == m) =================
        float G = 0.0f, c2A = 0.0f, c2H = 0.0f;
        float4 g4 = sg4[lane];
        float ga = gw * gh;
        int cell = (int)floorf(gy) * W_N + (int)floorf(gx);
        cell = min(max(cell, 0), HW_N - 1);
        int ccx = cell % W_N, ccy = cell / W_N;
        float best = -1.0f;
        int ai = 0; float aw = 1.0f, ah = 1.0f;
        #pragma unroll
        for (int aa = 0; aa < A_N; ++aa) {
            float anw = anchors[2 * aa], anh = anchors[2 * aa + 1];
            float atlx = (float)ccx + 0.5f - anw * 0.5f;
            float atly = (float)ccy + 0.5f - anh * 0.5f;
            float ix = fminf(atlx + anw, g4.z) - fmaxf(atlx, g4.x);
            float iy = fminf(atly + anh, g4.w) - fmaxf(atly, g4.y);
            float inter = fmaxf(ix, 0.0f) * fmaxf(iy, 0.0f);
            float ov = inter * fastrcp(anw * anh + ga - inter);
            if (ov > best) { best = ov; ai = aa; aw = anw; ah = anh; }
        }
        // winner = last valid m holding its key (lax.scan overwrite):
        // register-only duplicate scan via shuffles (invalid keys distinct)
        int mykey = valid ? (cell * A_N + ai) : (-1 - lane);
        bool winner = valid;
        for (int d = 1; d < M_N; ++d) {
            int ok = __shfl_down(mykey, d);
            if ((lane + d) < M_N && ok == mykey) winner = false;
        }

        if (winner) {
            size_t obase = ((size_t)b * (A_N * CH_N) + (size_t)ai * CH_N) * HW_N + cell;
            float o0 = outputs[obase + 0 * HW_N];
            float o1 = outputs[obase + 1 * HW_N];
            float o2 = outputs[obase + 2 * HW_N];
            float o3 = outputs[obase + 3 * HW_N];
            float o4 = outputs[obase + 4 * HW_N];
            float sx = sigmoidf_(o0), sy = sigmoidf_(o1);
            float ew = __expf(o2), eh = __expf(o3);
            float conf = sigmoidf_(o4);
            float px = sx + (float)ccx, py = sy + (float)ccy;
            float pw = ew * aw, ph = eh * ah;
            float tlx = px - pw * 0.5f, tly = py - ph * 0.5f;
            float brx = px + pw * 0.5f, bry = py + ph * 0.5f;
            float pa = pw * ph;

            float mi = 0.0f, maxdW = -1e30f;
            for (int mm = 0; mm < nobj; ++mm) {
                float4 g = sg4[mm];
                float gaM = (g.z - g.x) * (g.w - g.y);
                float ix = fminf(brx, g.z) - fmaxf(tlx, g.x);
                float iy = fminf(bry, g.w) - fmaxf(tly, g.y);
                float in = fmaxf(ix, 0.0f) * fmaxf(iy, 0.0f);
                mi = fmaxf(mi, in * fastrcp(pa + gaM - in));
                maxdW = fmaxf(maxdW, fmaf(3.0f, in, -(pa + gaM)));
            }

            float dcf = conf - mi;
            G = dcf * dcf;
            float bs = 2.0f - (pw / (float)W_N) * (ph / (float)H_N);
            float e0 = sx - (gx - (float)ccx);
            float e1 = sy - (gy - (float)ccy);
            float e2 = ew - gw / aw;
            float e3 = eh - gh / ah;
            G += bs * (e0 * e0 + e1 * e1 + e2 * e2 + e3 * e3);

            int cls = (int)tc;
            float mx = -1e30f, tv = 0.0f, logits[NCLS];
            #pragma unroll
            for (int c = 0; c < NCLS; ++c) {
                logits[c] = outputs[obase + (size_t)(5 + c) * HW_N];
                mx = fmaxf(mx, logits[c]);
            }
            float se = 0.0f;
            #pragma unroll
            for (int c = 0; c < NCLS; ++c) {
                se += __expf(logits[c] - mx);
                if (c == cls) tv = logits[c];
            }
            G += (mx + __logf(se)) - tv;

            c2A = conf * conf;                       // noobj-sum corrections
            c2H = (maxdW >= 0.0f) ? c2A : 0.0f;      // same ">=0.5" algebra
        }
        #pragma unroll
        for (int off = 32; off > 0; off >>= 1) {
            G   += __shfl_down(G, off);
            c2A += __shfl_down(c2A, off);
            c2H += __shfl_down(c2H, off);
        }
        if (lane == 0) {
            Gb[b] = G; Asub[b] = c2A; Hsub[b] = c2H; nobjArr[b] = nobj;
        }
    } else {
        // ========== noobj path: 2 locations/thread + wave y-prune ==========
        float tlx0, tly0, brx0, bry0, pa0, tlx1, tly1, brx1, bry1, pa1;
        if (act) {
            int wy = hw0 / W_N;
            int wx = hw0 - wy * W_N;        // hw0 even, W even -> same row
            float aw = anchors[2 * a], ah = anchors[2 * a + 1];
            float sx0 = sigmoidf_(O0.x), sx1 = sigmoidf_(O0.y);
            float sy0 = sigmoidf_(O1.x), sy1 = sigmoidf_(O1.y);
            float pw0 = __expf(O2.x) * aw, pw1 = __expf(O2.y) * aw;
            float ph0 = __expf(O3.x) * ah, ph1 = __expf(O3.y) * ah;
            float px0 = sx0 + (float)wx, px1 = sx1 + (float)(wx + 1);
            float py0 = sy0 + (float)wy, py1 = sy1 + (float)wy;
            tlx0 = px0 - pw0 * 0.5f; tly0 = py0 - ph0 * 0.5f;
            brx0 = px0 + pw0 * 0.5f; bry0 = py0 + ph0 * 0.5f;
            tlx1 = px1 - pw1 * 0.5f; tly1 = py1 - ph1 * 0.5f;
            brx1 = px1 + pw1 * 0.5f; bry1 = py1 + ph1 * 0.5f;
            pa0 = pw0 * ph0; pa1 = pw1 * ph1;
        } else {
            // sentinel: iy always negative, pa huge -> all tests false
            tlx0 = tlx1 = SENT; tly0 = tly1 = SENT;
            brx0 = brx1 = -SENT; bry0 = bry1 = -SENT;
            pa0 = pa1 = SENT;
        }

        // maxs = max over gts of (3*inter - ga); iou>=0.5 <=> maxs >= pa
        float maxs0 = -1e30f, maxs1 = -1e30f;
        for (int m = 0; m < nobj; ++m) {
            float4 g = sg4[m];
            float iy0 = fminf(bry0, g.w) - fmaxf(tly0, g.y);
            float iy1 = fminf(bry1, g.w) - fmaxf(tly1, g.y);
            if (__any(fmaxf(iy0, iy1) > 0.0f)) {     // exact wave-uniform prune
                float ga = (g.z - g.x) * (g.w - g.y);
                float ix0 = fminf(brx0, g.z) - fmaxf(tlx0, g.x);
                float in0 = fmaxf(ix0, 0.0f) * fmaxf(iy0, 0.0f);
                maxs0 = fmaxf(maxs0, fmaf(3.0f, in0, -ga));
                float ix1 = fminf(brx1, g.z) - fmaxf(tlx1, g.x);
                float in1 = fmaxf(ix1, 0.0f) * fmaxf(iy1, 0.0f);
                maxs1 = fmaxf(maxs1, fmaf(3.0f, in1, -ga));
            }
        }

        float locA = 0.0f, locH = 0.0f;
        bool any = false;
        if (act) {
            float conf0 = sigmoidf_(O4.x), conf1 = sigmoidf_(O4.y);
            float c20 = conf0 * conf0, c21 = conf1 * conf1;
            locA = c20 + c21;
            locH = (maxs0 >= pa0 ? c20 : 0.0f) + (maxs1 >= pa1 ? c21 : 0.0f);
            any = (maxs0 > pa0) || (maxs1 > pa1);
        }

        int wany = __any(any) ? 1 : 0;
        #pragma unroll
        for (int off = 32; off > 0; off >>= 1) {
            locA += __shfl_down(locA, off);
            locH += __shfl_down(locH, off);
        }
        int w = tid >> 6;
        if (lane == 0) { rA[w] = locA; rH[w] = locH; rAny[w] = wany; }
        __syncthreads();
        if (tid == 0) {
            int nb = blk - WIN_BLKS;
            A_part[nb] = rA[0] + rA[1] + rA[2];
            H_part[nb] = rH[0] + rH[1] + rH[2];
            any_part[nb] = rAny[0] | rAny[1] | rAny[2];
        }
    }
}

// ---------------------------------------------------------------------------
// Finish: 128 threads, one per batch; fixed-order deterministic reduction.
// ---------------------------------------------------------------------------
__global__ __launch_bounds__(128) void finish_kernel(
    const float* __restrict__ A_part, const float* __restrict__ H_part,
    const int* __restrict__ any_part,
    const float* __restrict__ Gb, const float* __restrict__ Asub,
    const float* __restrict__ Hsub, const int* __restrict__ nobjArr,
    float* __restrict__ out) {
    int t = threadIdx.x;  // == b
    float A = -Asub[t], Hs = -Hsub[t];
    int any = 0;
    #pragma unroll
    for (int j = 0; j < SLOTS_PER_B; ++j) {
        A += A_part[t * SLOTS_PER_B + j];
        Hs += H_part[t * SLOTS_PER_B + j];
        any |= any_part[t * SLOTS_PER_B + j];
    }
    float noobj = (nobjArr[t] > 0) ? (A - (any ? Hs : 0.0f)) : 0.0f;
    float v = Gb[t] + noobj;
    #pragma unroll
    for (int off = 32; off > 0; off >>= 1) v += __shfl_down(v, off);
    __shared__ float r[2];
    if ((t & 63) == 0) r[t >> 6] = v;
    __syncthreads();
    if (t == 0) out[0] = (r[0] + r[1]) / (float)B_N;
}

extern "C" void kernel_launch(void* const* d_in, const int* in_sizes, int n_in,
                              void* d_out, int out_size, void* d_ws, size_t ws_size,
                              hipStream_t stream) {
    const float* outputs = (const float*)d_in[0];
    const float* targets = (const float*)d_in[1];
    const float* anchors = (const float*)d_in[2];
    float* out = (float*)d_out;

    char* ws = (char*)d_ws;
    size_t off = 0;
    float* A_part = (float*)(ws + off); off += 4 * (size_t)NOOBJ_BLKS;
    float* H_part = (float*)(ws + off); off += 4 * (size_t)NOOBJ_BLKS;
    int* any_part = (int*)(ws + off);   off += 4 * (size_t)NOOBJ_BLKS;
    float* Gb = (float*)(ws + off);     off += 4 * B_N;
    float* Asub = (float*)(ws + off);   off += 4 * B_N;
    float* Hsub = (float*)(ws + off);   off += 4 * B_N;
    int* nobjArr = (int*)(ws + off);    off += 4 * B_N;
    // every slot above is unconditionally written each call -> no memset needed

    main_kernel<<<WIN_BLKS + NOOBJ_BLKS, BLK_T, 0, stream>>>(
        outputs, targets, anchors,
        A_part, H_part, any_part, Gb, Asub, Hsub, nobjArr);

    finish_kernel<<<1, 128, 0, stream>>>(A_part, H_part, any_part,
                                         Gb, Asub, Hsub, nobjArr, out);
}

// Round 9
// 18.547 us; speedup vs baseline: 1.7159x; 1.2207x over previous
//
#include <hip/hip_runtime.h>
#include <math.h>

#define NCLS 20
#define B_N 128
#define A_N 5
#define H_N 26
#define W_N 26
#define HW_N (H_N * W_N)            // 676
#define M_N 64
#define CH_N (5 + NCLS)             // 25
#define HALF_LOC (HW_N / 2)         // 338 locations per half-plane
#define HALF_T (HALF_LOC / 2)       // 169 active threads (2 locs each)
#define BLK_T 192                   // 3 waves
#define WIN_BLKS B_N                // 128 winner blocks (first in grid)
#define NOOBJ_BLKS (B_N * A_N * 2)  // 1280 half-plane blocks
#define SLOTS_PER_B (A_N * 2)       // 10 per-block slots per batch

typedef _Float16 h2 __attribute__((ext_vector_type(2)));

__device__ __forceinline__ float fastrcp(float x) { return __builtin_amdgcn_rcpf(x); }
__device__ __forceinline__ float sigmoidf_(float x) { return fastrcp(1.0f + __expf(-x)); }
__device__ __forceinline__ h2 h2min(h2 a, h2 b) { return __builtin_elementwise_min(a, b); }
__device__ __forceinline__ h2 h2max(h2 a, h2 b) { return __builtin_elementwise_max(a, b); }
__device__ __forceinline__ h2 h2fma(h2 a, h2 b, h2 c) { return __builtin_elementwise_fma(a, b, c); }
__device__ __forceinline__ unsigned packh2(float lo, float hi) {
    h2 v; v.x = (_Float16)lo; v.y = (_Float16)hi;
    return __builtin_bit_cast(unsigned, v);
}
__device__ __forceinline__ h2 ash2(unsigned u) { return __builtin_bit_cast(h2, u); }

// ---------------------------------------------------------------------------
// Main kernel: 128 winner blocks + 1280 noobj half-plane blocks.
// noobj loop: packed-f16 sign test (2 locations per v_pk op), branch-free,
// 4-wide manual unroll, dual max accumulators. Winner path exact fp32.
// ---------------------------------------------------------------------------
__global__ __launch_bounds__(BLK_T) void main_kernel(
    const float* __restrict__ outputs, const float* __restrict__ targets,
    const float* __restrict__ anchors,
    float* __restrict__ A_part, float* __restrict__ H_part,
    int* __restrict__ any_part,
    float* __restrict__ Gb, float* __restrict__ Asub, float* __restrict__ Hsub,
    int* __restrict__ nobjArr) {
    int blk = blockIdx.x;
    bool winnerBlk = (blk < WIN_BLKS);
    int tid = threadIdx.x;
    int lane = tid & 63;

    int b, a, half;
    if (winnerBlk) { b = blk; a = 0; half = 0; }
    else {
        int nb = blk - WIN_BLKS;
        int plane = nb >> 1; half = nb & 1;
        b = plane / A_N; a = plane % A_N;
    }

    __shared__ float4 sg4[M_N];      // fp32 boxes (winner blocks only)
    __shared__ uint4 sgq[M_N];       // 4x duplicated-half2 fields (noobj)
    __shared__ unsigned snga[M_N];   // duplicated -ga as half2 bits (noobj)
    __shared__ int skey[M_N];
    __shared__ int snobj;
    __shared__ float rA[3], rH[3];
    __shared__ int rAny[3];

    // ---- early-issue O-plane loads (noobj), overlap with gt staging ----
    bool act = false;
    float2 O0, O1, O2, O3, O4;
    int hw0 = 0;
    if (!winnerBlk) {
        act = (tid < HALF_T);
        if (act) {
            hw0 = half * HALF_LOC + tid * 2;
            const float* op = outputs +
                ((size_t)b * (A_N * CH_N) + (size_t)a * CH_N) * HW_N + hw0;
            O0 = *(const float2*)(op + 0 * HW_N);
            O1 = *(const float2*)(op + 1 * HW_N);
            O2 = *(const float2*)(op + 2 * HW_N);
            O3 = *(const float2*)(op + 3 * HW_N);
            O4 = *(const float2*)(op + 4 * HW_N);
        }
    }

    // ---- staging: wave 0 builds gt boxes in LDS ----
    float tc = 0, gx = 0, gy = 0, gw = 0, gh = 0;
    bool valid = false;
    if (tid < M_N) {
        const float* trow = targets + ((size_t)b * M_N + tid) * 5;
        tc = trow[0];
        float tx = trow[1], ty = trow[2], tw = trow[3], th = trow[4];
        valid = (tc + tx + ty + tw + th) > 0.0f;    // valid rows are a prefix
        unsigned long long mask = __ballot(valid);
        if (tid == 0) snobj = __popcll(mask);
        gx = tx * (float)W_N; gy = ty * (float)H_N;
        gw = tw * (float)W_N; gh = th * (float)H_N;
        float x0 = gx - gw * 0.5f, y0 = gy - gh * 0.5f;
        float x1 = gx + gw * 0.5f, y1 = gy + gh * 0.5f;
        if (winnerBlk) {
            sg4[tid] = make_float4(x0, y0, x1, y1);
        } else {
            // invalid rows are zero boxes -> inter clamps to 0, -ga=0 (harmless)
            uint4 q;
            q.x = packh2(x0, x0); q.y = packh2(y0, y0);
            q.z = packh2(x1, x1); q.w = packh2(y1, y1);
            sgq[tid] = q;
            snga[tid] = packh2(-(gw * gh), -(gw * gh));
        }
    }
    __syncthreads();
    int nobj = snobj;

    if (winnerBlk) {
        if (tid >= M_N) return;                     // waves 1,2 done
        // ================= winner path (wave 0, lane == m) =================
        float G = 0.0f, c2A = 0.0f, c2H = 0.0f;
        float4 g4 = sg4[lane];
        float ga = gw * gh;
        int cell = (int)floorf(gy) * W_N + (int)floorf(gx);
        cell = min(max(cell, 0), HW_N - 1);
        int ccx = cell % W_N, ccy = cell / W_N;
        float best = -1.0f;
        int ai = 0; float aw = 1.0f, ah = 1.0f;
        #pragma unroll
        for (int aa = 0; aa < A_N; ++aa) {
            float anw = anchors[2 * aa], anh = anchors[2 * aa + 1];
            float atlx = (float)ccx + 0.5f - anw * 0.5f;
            float atly = (float)ccy + 0.5f - anh * 0.5f;
            float ix = fminf(atlx + anw, g4.z) - fmaxf(atlx, g4.x);
            float iy = fminf(atly + anh, g4.w) - fmaxf(atly, g4.y);
            float inter = fmaxf(ix, 0.0f) * fmaxf(iy, 0.0f);
            float ov = inter * fastrcp(anw * anh + ga - inter);
            if (ov > best) { best = ov; ai = aa; aw = anw; ah = anh; }
        }
        skey[lane] = valid ? (cell * A_N + ai) : (-1 - lane);
        __syncthreads();
        // winner = last valid m holding its key (lax.scan overwrite)
        bool winner = valid;
        if (valid) {
            int mykey = skey[lane];
            for (int mm = lane + 1; mm < M_N; ++mm)
                if (skey[mm] == mykey) winner = false;
        }

        if (winner) {
            size_t obase = ((size_t)b * (A_N * CH_N) + (size_t)ai * CH_N) * HW_N + cell;
            float o0 = outputs[obase + 0 * HW_N];
            float o1 = outputs[obase + 1 * HW_N];
            float o2 = outputs[obase + 2 * HW_N];
            float o3 = outputs[obase + 3 * HW_N];
            float o4 = outputs[obase + 4 * HW_N];
            float sx = sigmoidf_(o0), sy = sigmoidf_(o1);
            float ew = __expf(o2), eh = __expf(o3);
            float conf = sigmoidf_(o4);
            float px = sx + (float)ccx, py = sy + (float)ccy;
            float pw = ew * aw, ph = eh * ah;
            float tlx = px - pw * 0.5f, tly = py - ph * 0.5f;
            float brx = px + pw * 0.5f, bry = py + ph * 0.5f;
            float pa = pw * ph;

            float mi = 0.0f, maxdW = -1e30f;
            for (int mm = 0; mm < nobj; ++mm) {
                float4 g = sg4[mm];
                float gaM = (g.z - g.x) * (g.w - g.y);
                float ix = fminf(brx, g.z) - fmaxf(tlx, g.x);
                float iy = fminf(bry, g.w) - fmaxf(tly, g.y);
                float in = fmaxf(ix, 0.0f) * fmaxf(iy, 0.0f);
                mi = fmaxf(mi, in * fastrcp(pa + gaM - in));
                maxdW = fmaxf(maxdW, fmaf(3.0f, in, -(pa + gaM)));
            }

            float dcf = conf - mi;
            G = dcf * dcf;
            float bs = 2.0f - (pw / (float)W_N) * (ph / (float)H_N);
            float e0 = sx - (gx - (float)ccx);
            float e1 = sy - (gy - (float)ccy);
            float e2 = ew - gw / aw;
            float e3 = eh - gh / ah;
            G += bs * (e0 * e0 + e1 * e1 + e2 * e2 + e3 * e3);

            int cls = (int)tc;
            float mx = -1e30f, tv = 0.0f, logits[NCLS];
            #pragma unroll
            for (int c = 0; c < NCLS; ++c) {
                logits[c] = outputs[obase + (size_t)(5 + c) * HW_N];
                mx = fmaxf(mx, logits[c]);
            }
            float se = 0.0f;
            #pragma unroll
            for (int c = 0; c < NCLS; ++c) {
                se += __expf(logits[c] - mx);
                if (c == cls) tv = logits[c];
            }
            G += (mx + __logf(se)) - tv;

            c2A = conf * conf;                       // noobj-sum corrections
            c2H = (maxdW >= 0.0f) ? c2A : 0.0f;
        }
        #pragma unroll
        for (int off = 32; off > 0; off >>= 1) {
            G   += __shfl_down(G, off);
            c2A += __shfl_down(c2A, off);
            c2H += __shfl_down(c2H, off);
        }
        if (lane == 0) {
            Gb[b] = G; Asub[b] = c2A; Hsub[b] = c2H; nobjArr[b] = nobj;
        }
    } else {
        // ========= noobj path: packed-f16, 2 locations/thread =========
        float pa0 = 1e30f, pa1 = 1e30f;
        h2 tlxH, tlyH, brxH, bryH;
        {
            float tlx0 = 0, tly0 = 0, brx0 = 0, bry0 = 0;
            float tlx1 = 0, tly1 = 0, brx1 = 0, bry1 = 0;
            if (act) {
                int wy = hw0 / W_N;
                int wx = hw0 - wy * W_N;    // hw0 even, W even -> same row
                float aw = anchors[2 * a], ah = anchors[2 * a + 1];
                float sx0 = sigmoidf_(O0.x), sx1 = sigmoidf_(O0.y);
                float sy0 = sigmoidf_(O1.x), sy1 = sigmoidf_(O1.y);
                float pw0 = __expf(O2.x) * aw, pw1 = __expf(O2.y) * aw;
                float ph0 = __expf(O3.x) * ah, ph1 = __expf(O3.y) * ah;
                float px0 = sx0 + (float)wx, px1 = sx1 + (float)(wx + 1);
                float py0 = sy0 + (float)wy, py1 = sy1 + (float)wy;
                tlx0 = px0 - pw0 * 0.5f; tly0 = py0 - ph0 * 0.5f;
                brx0 = px0 + pw0 * 0.5f; bry0 = py0 + ph0 * 0.5f;
                tlx1 = px1 - pw1 * 0.5f; tly1 = py1 - ph1 * 0.5f;
                brx1 = px1 + pw1 * 0.5f; bry1 = py1 + ph1 * 0.5f;
                pa0 = pw0 * ph0; pa1 = pw1 * ph1;
            }
            tlxH = ash2(packh2(tlx0, tlx1));
            tlyH = ash2(packh2(tly0, tly1));
            brxH = ash2(packh2(brx0, brx1));
            bryH = ash2(packh2(bry0, bry1));
        }

        h2 h3; h3.x = (_Float16)3.0f; h3.y = (_Float16)3.0f;
        h2 hzero; hzero.x = (_Float16)0.0f; hzero.y = (_Float16)0.0f;
        h2 msA; msA.x = (_Float16)(-60000.0f); msA.y = (_Float16)(-60000.0f);
        h2 msB = msA;

        // s = 3*inter - ga (packed over 2 locations); iou>=0.5 <=> s >= pa
        #define IOU_STEP(Q, NGA, ACC)                                          \
        {                                                                      \
            h2 gx2 = ash2((Q).x), gy2 = ash2((Q).y);                           \
            h2 gz2 = ash2((Q).z), gw2 = ash2((Q).w);                           \
            h2 ix = h2min(brxH, gz2) - h2max(tlxH, gx2);                       \
            h2 iy = h2min(bryH, gw2) - h2max(tlyH, gy2);                       \
            h2 in = h2max(ix, hzero) * h2max(iy, hzero);                       \
            ACC = h2max(ACC, h2fma(h3, in, NGA));                              \
        }

        for (int m = 0; m < nobj; m += 4) {
            uint4 q0 = sgq[m + 0], q1 = sgq[m + 1];
            uint4 q2 = sgq[m + 2], q3 = sgq[m + 3];
            h2 n0 = ash2(snga[m + 0]), n1 = ash2(snga[m + 1]);
            h2 n2 = ash2(snga[m + 2]), n3 = ash2(snga[m + 3]);
            IOU_STEP(q0, n0, msA);
            IOU_STEP(q1, n1, msB);
            IOU_STEP(q2, n2, msA);
            IOU_STEP(q3, n3, msB);
        }
        h2 ms = h2max(msA, msB);
        float ms0 = (float)ms.x, ms1 = (float)ms.y;

        float locA = 0.0f, locH = 0.0f;
        bool any = false;
        if (act) {
            float conf0 = sigmoidf_(O4.x), conf1 = sigmoidf_(O4.y);
            float c20 = conf0 * conf0, c21 = conf1 * conf1;
            locA = c20 + c21;
            locH = (ms0 >= pa0 ? c20 : 0.0f) + (ms1 >= pa1 ? c21 : 0.0f);
            any = (ms0 > pa0) || (ms1 > pa1);
        }

        int wany = __any(any) ? 1 : 0;
        #pragma unroll
        for (int off = 32; off > 0; off >>= 1) {
            locA += __shfl_down(locA, off);
            locH += __shfl_down(locH, off);
        }
        int w = tid >> 6;
        if (lane == 0) { rA[w] = locA; rH[w] = locH; rAny[w] = wany; }
        __syncthreads();
        if (tid == 0) {
            int nb = blk - WIN_BLKS;
            A_part[nb] = rA[0] + rA[1] + rA[2];
            H_part[nb] = rH[0] + rH[1] + rH[2];
            any_part[nb] = rAny[0] | rAny[1] | rAny[2];
        }
    }
}

// ---------------------------------------------------------------------------
// Finish: 128 threads, one per batch; fixed-order deterministic reduction.
// ---------------------------------------------------------------------------
__global__ __launch_bounds__(128) void finish_kernel(
    const float* __restrict__ A_part, const float* __restrict__ H_part,
    const int* __restrict__ any_part,
    const float* __restrict__ Gb, const float* __restrict__ Asub,
    const float* __restrict__ Hsub, const int* __restrict__ nobjArr,
    float* __restrict__ out) {
    int t = threadIdx.x;  // == b
    float A = -Asub[t], Hs = -Hsub[t];
    int any = 0;
    #pragma unroll
    for (int j = 0; j < SLOTS_PER_B; ++j) {
        A += A_part[t * SLOTS_PER_B + j];
        Hs += H_part[t * SLOTS_PER_B + j];
        any |= any_part[t * SLOTS_PER_B + j];
    }
    float noobj = (nobjArr[t] > 0) ? (A - (any ? Hs : 0.0f)) : 0.0f;
    float v = Gb[t] + noobj;
    #pragma unroll
    for (int off = 32; off > 0; off >>= 1) v += __shfl_down(v, off);
    __shared__ float r[2];
    if ((t & 63) == 0) r[t >> 6] = v;
    __syncthreads();
    if (t == 0) out[0] = (r[0] + r[1]) / (float)B_N;
}

extern "C" void kernel_launch(void* const* d_in, const int* in_sizes, int n_in,
                              void* d_out, int out_size, void* d_ws, size_t ws_size,
                              hipStream_t stream) {
    const float* outputs = (const float*)d_in[0];
    const float* targets = (const float*)d_in[1];
    const float* anchors = (const float*)d_in[2];
    float* out = (float*)d_out;

    char* ws = (char*)d_ws;
    size_t off = 0;
    float* A_part = (float*)(ws + off); off += 4 * (size_t)NOOBJ_BLKS;
    float* H_part = (float*)(ws + off); off += 4 * (size_t)NOOBJ_BLKS;
    int* any_part = (int*)(ws + off);   off += 4 * (size_t)NOOBJ_BLKS;
    float* Gb = (float*)(ws + off);     off += 4 * B_N;
    float* Asub = (float*)(ws + off);   off += 4 * B_N;
    float* Hsub = (float*)(ws + off);   off += 4 * B_N;
    int* nobjArr = (int*)(ws + off);    off += 4 * B_N;
    // every slot above is unconditionally written each call -> no memset needed

    main_kernel<<<WIN_BLKS + NOOBJ_BLKS, BLK_T, 0, stream>>>(
        outputs, targets, anchors,
        A_part, H_part, any_part, Gb, Asub, Hsub, nobjArr);

    finish_kernel<<<1, 128, 0, stream>>>(A_part, H_part, any_part,
                                         Gb, Asub, Hsub, nobjArr, out);
}